// Round 6
// baseline (159.063 us; speedup 1.0000x reference)
//
#include <hip/hip_runtime.h>
#include <math.h>

// Problem constants: BSZ=64, BEAM=8, VOCAB=50257, STEP=5
// R15: NT x MLP interaction probe. Ledger: R10 pinned 13-deep burst on the
// L2-allocating path = neutral (allocate/evict machinery was the wall, extra
// in-flight just queued). R14 NT loads alone (groups of 4) = -10us total,
// rowtop ~61 -> ~50us = 2.06 TB/s (first confirmed mechanism: L2-allocate
// path). On the NT/L3-direct path, latency is longer and allocate cost is
// gone -> throughput = outstanding-lines/latency, so per-wave MLP may now
// be the binding term. R15 = R14's aligned NT stream with the load issue
// restructured to a FULL 13-load asm-pinned burst (single vmcnt(0) drain),
// lb(256,4) so ~90 pinned VGPRs fit (4 blocks/CU, 16 waves/CU; occupancy
// level already shown neutral R9 vs R11). All else identical to R14:
// aligned head/tail peel, TAU prefilter + LDS append + chunked bitonic
// top-16, exact-T tournament fallback (plain loads, unreachable on N(0,1)).
// Decision rule: neutral => all in-kernel levers exhausted, declare
// roofline (rowtop within ~25% of the ~2.5-3.2 TB/s read-path floor; rest
// of dur_us is fixed harness reset traffic).
#define BSZ   64
#define BEAM  8
#define VOCAB 50257
#define NSTEP 5
#define K     16
#define DIV_RATE 0.5f
#define NSEG  4
#define SEGF4 3141               // f4 per segment (segs 0..2; seg 3: nf4-9423)
#define QITER 12                 // 12*256 = 3072 f4 unconditional per seg
#define TAU   2.3f               // P(N(0,1)>=2.3)=0.0107 -> ~134 cands/seg
#define SBUF_CAP 1024            // >= fallback proof bound 16*55=880

typedef unsigned long long u64;
typedef unsigned u32;
typedef float f32x4 __attribute__((ext_vector_type(4)));

// order-preserving float<->uint (monotone for all non-NaN)
__device__ __forceinline__ u32 f2s(float f) {
    u32 u = __float_as_uint(f);
    return (u & 0x80000000u) ? ~u : (u | 0x80000000u);
}
__device__ __forceinline__ float s2f(u32 s) {
    u32 u = (s & 0x80000000u) ? (s ^ 0x80000000u) : ~s;
    return __uint_as_float(u);
}

// non-temporal 16B load: global_load_dwordx4 with nt (bypass L2 allocate)
__device__ __forceinline__ f32x4 ntload(const f32x4* p) {
    return __builtin_nontemporal_load(p);
}

// wave(64)-wide max of a u64 key (validated R1-R14)
__device__ __forceinline__ u64 wmax64(u64 k) {
#pragma unroll
    for (int off = 32; off > 0; off >>= 1) {
        u32 lo = __shfl_xor((u32)k, off, 64);
        u32 hi = __shfl_xor((u32)(k >> 32), off, 64);
        u64 o = ((u64)hi << 32) | lo;
        if (o > k) k = o;
    }
    return k;
}

#define BSTEPS(X)                                                            \
    X(2, 1)                                                                  \
    X(4, 2)  X(4, 1)                                                         \
    X(8, 4)  X(8, 2)  X(8, 1)                                                \
    X(16, 8) X(16, 4) X(16, 2) X(16, 1)                                      \
    X(32, 16) X(32, 8) X(32, 4) X(32, 2) X(32, 1)                            \
    X(64, 32) X(64, 16) X(64, 8) X(64, 4) X(64, 2) X(64, 1)

// u32 ascending bitonic sort across 64 lanes (validated R3-R14)
__device__ __forceinline__ u32 bitonic64_asc(u32 v, int lane) {
#define BS32(K_, J_)                                                         \
    {                                                                        \
        u32 o = __shfl_xor(v, (J_), 64);                                     \
        bool tmin = ((lane & (J_)) == 0) == ((lane & (K_)) == 0);            \
        v = tmin ? (v < o ? v : o) : (v > o ? v : o);                        \
    }
    BSTEPS(BS32)
#undef BS32
    return v;
}

// u64 ascending bitonic sort across 64 lanes (same network, 2 shfl/step)
__device__ __forceinline__ u64 bitonic64_asc_u64(u64 v, int lane) {
#define BS64(K_, J_)                                                         \
    {                                                                        \
        u32 lo = __shfl_xor((u32)v, (J_), 64);                               \
        u32 hi = __shfl_xor((u32)(v >> 32), (J_), 64);                       \
        u64 o = ((u64)hi << 32) | lo;                                        \
        bool tmin = ((lane & (J_)) == 0) == ((lane & (K_)) == 0);            \
        v = tmin ? (v < o ? v : o) : (v > o ? v : o);                        \
    }
    BSTEPS(BS64)
#undef BS64
    return v;
}

// Phase 1: one 256-thread block per (row, quarter). FULL 13-load NT burst
// (asm-pinned, all issued before first consume), max tree, TAU prefilter
// scanning the pinned registers, rare atomic append into LDS. Head/tail
// scalars of the row handled by tid 0 of seg 0 / seg 3. Tail: wave 0 sorts
// candidates via chunked u64 bitonic, writes sorted top-16.
// key = f2s(value)<<32 | ~vocab_idx (bias deferred: uniform per row).
__global__ __launch_bounds__(256, 4) void rowtop(
    const float* __restrict__ lprobs, u64* __restrict__ segk)
{
    const int tid  = threadIdx.x;
    const int lane = tid & 63;
    const int wave = tid >> 6;       // 0..3
    const int seg  = blockIdx.x;     // 0..3
    const int row  = blockIdx.y;     // 0..511

    const int head = (4 - (row & 3)) & 3;       // scalars before aligned bulk
    const int nf4  = (VOCAB - head) >> 2;       // 12563 or 12564
    const int tail = VOCAB - head - 4 * nf4;    // 0..3 scalars after bulk

    const float* rowp = lprobs + (size_t)row * VOCAB;
    const f32x4* rp4  = (const f32x4*)(rowp + head);   // truly 16B-aligned
    const int segBase = seg * SEGF4;
    const int segCnt  = (seg < NSEG - 1) ? SEGF4 : (nf4 - (NSEG - 1) * SEGF4);
    const f32x4* base = rp4 + segBase + tid;
    const int rem = segCnt - QITER * 256;       // 68 or 69

    // ---- burst: 12 unconditional + 1 predicated NT loads, all issued ----
    f32x4 a0  = ntload(base + 0 * 256);
    f32x4 a1  = ntload(base + 1 * 256);
    f32x4 a2  = ntload(base + 2 * 256);
    f32x4 a3  = ntload(base + 3 * 256);
    f32x4 a4  = ntload(base + 4 * 256);
    f32x4 a5  = ntload(base + 5 * 256);
    f32x4 a6  = ntload(base + 6 * 256);
    f32x4 a7  = ntload(base + 7 * 256);
    f32x4 a8  = ntload(base + 8 * 256);
    f32x4 a9  = ntload(base + 9 * 256);
    f32x4 a10 = ntload(base + 10 * 256);
    f32x4 a11 = ntload(base + 11 * 256);
    f32x4 a12 = {-INFINITY, -INFINITY, -INFINITY, -INFINITY};
    if (tid < rem) a12 = ntload(base + 12 * 256);
    float extra = -INFINITY;                    // row tail scalars (<=3)
    float extra1 = -INFINITY, extra2 = -INFINITY;
    if (seg == NSEG - 1 && tid == 0) {
        if (tail > 0) extra  = rowp[head + 4 * nf4 + 0];
        if (tail > 1) extra1 = rowp[head + 4 * nf4 + 1];
        if (tail > 2) extra2 = rowp[head + 4 * nf4 + 2];
    }
    float h0 = -INFINITY, h1 = -INFINITY, h2 = -INFINITY;  // head scalars
    if (seg == 0 && tid == 0) {
        if (head > 0) h0 = rowp[0];
        if (head > 1) h1 = rowp[1];
        if (head > 2) h2 = rowp[2];
    }

    // Pin: forces all 13 vmem ops issued before first consume (full MLP on
    // the NT path) and forbids rematerialization in the filter phase.
    asm volatile(""
                 : "+v"(a0), "+v"(a1), "+v"(a2), "+v"(a3), "+v"(a4),
                   "+v"(a5), "+v"(a6), "+v"(a7), "+v"(a8), "+v"(a9),
                   "+v"(a10), "+v"(a11), "+v"(a12));

#define MAX4(v) fmaxf(fmaxf((v).x, (v).y), fmaxf((v).z, (v).w))
    float m = fmaxf(
        fmaxf(fmaxf(fmaxf(MAX4(a0), MAX4(a1)), fmaxf(MAX4(a2), MAX4(a3))),
              fmaxf(fmaxf(MAX4(a4), MAX4(a5)), fmaxf(MAX4(a6), MAX4(a7)))),
        fmaxf(fmaxf(fmaxf(MAX4(a8), MAX4(a9)), fmaxf(MAX4(a10), MAX4(a11))),
              MAX4(a12)));
    m = fmaxf(m, fmaxf(fmaxf(h0, h1), fmaxf(h2, fmaxf(extra, fmaxf(extra1, extra2)))));
#undef MAX4

    __shared__ u64 sbuf[SBUF_CAP];
    __shared__ u32 smax[64];         // 4 waves x top-16 maxima (fallback)
    __shared__ u32 sT;
    __shared__ int scnt;
    if (tid == 0) scnt = 0;
    __syncthreads();

#define APPTH(xx, ei, TH)                                                    \
    if ((xx) >= (TH)) {                                                      \
        int p = atomicAdd(&scnt, 1);                                         \
        if (p < SBUF_CAP) sbuf[p] = ((u64)f2s(xx) << 32) | (u32)~(u32)(ei);  \
    }
#define APP4(av, c4, TH)                                                     \
    {                                                                        \
        float m4 = fmaxf(fmaxf((av).x, (av).y), fmaxf((av).z, (av).w));      \
        if (m4 >= (TH)) {                                                    \
            int b4 = head + 4 * (segBase + (c4) * 256 + tid);                \
            APPTH((av).x, b4 + 0, TH) APPTH((av).y, b4 + 1, TH)              \
            APPTH((av).z, b4 + 2, TH) APPTH((av).w, b4 + 3, TH)              \
        }                                                                    \
    }
#define APPEDGE(TH)                                                          \
    if (seg == 0 && tid == 0) {                                              \
        APPTH(h0, 0, TH) APPTH(h1, 1, TH) APPTH(h2, 2, TH)                   \
    }                                                                        \
    if (seg == NSEG - 1 && tid == 0) {                                       \
        int e0 = head + 4 * nf4;                                             \
        APPTH(extra, e0 + 0, TH) APPTH(extra1, e0 + 1, TH)                   \
        APPTH(extra2, e0 + 2, TH)                                            \
    }

    // ---- filter pinned registers against TAU ----
    APP4(a0, 0, TAU)  APP4(a1, 1, TAU)  APP4(a2, 2, TAU)   APP4(a3, 3, TAU)
    APP4(a4, 4, TAU)  APP4(a5, 5, TAU)  APP4(a6, 6, TAU)   APP4(a7, 7, TAU)
    APP4(a8, 8, TAU)  APP4(a9, 9, TAU)  APP4(a10, 10, TAU) APP4(a11, 11, TAU)
    APP4(a12, 12, TAU)                       // -INF lanes never pass
    APPEDGE(TAU)
    __syncthreads();

    int n = scnt;
    if (n < K || n > SBUF_CAP) {
        // ---- exact fallback (unreachable on N(0,1) bench data) ----
        // T = exact 16th largest of 256 thread-maxima; candidates >= T are
        // bounded by 16 owners x <=55 elems = 880 <= SBUF_CAP.
        u32 vs = bitonic64_asc(f2s(m), lane);
        if (lane >= 48) smax[wave * 16 + (lane - 48)] = vs;
        __syncthreads();
        if (wave == 0) {
            u32 w = bitonic64_asc(smax[lane], lane);
            if (lane == 48) sT = w;
        }
        if (tid == 0) scnt = 0;
        __syncthreads();
        const float T = s2f(sT);
        APP4(a0, 0, T)  APP4(a1, 1, T)  APP4(a2, 2, T)   APP4(a3, 3, T)
        APP4(a4, 4, T)  APP4(a5, 5, T)  APP4(a6, 6, T)   APP4(a7, 7, T)
        APP4(a8, 8, T)  APP4(a9, 9, T)  APP4(a10, 10, T) APP4(a11, 11, T)
        APP4(a12, 12, T)
        APPEDGE(T)
        __syncthreads();
        n = scnt > SBUF_CAP ? SBUF_CAP : scnt;
    }
#undef APPEDGE
#undef APP4
#undef APPTH

    // ---- wave 0: sorted top-16 of candidates via chunked u64 bitonic ----
    if (wave == 0) {
        u64 run = 0;
        for (int b0 = 0; b0 < n; b0 += 48) {
            u64 v = run;                          // lanes 48..63 keep top-16
            if (lane < 48) { int p = b0 + lane; v = (p < n) ? sbuf[p] : 0; }
            v = bitonic64_asc_u64(v, lane);
            run = (lane >= 48) ? v : 0;
        }
        if (lane >= 48) {                         // rank 0 = best
            int r = 63 - lane;
            segk[((size_t)row * NSEG + seg) * K + r] = run;
        }
    }
}

// Phase 2: block b, wave j: merge beam j's four sorted 16-lists (one u64
// bitonic over 64 real keys; rank = lane position), apply bias + sibling
// penalty, wave 0 runs the validated 128->16 extraction.
__global__ __launch_bounds__(512) void finalize(
    const u64* __restrict__ segk, const float* __restrict__ scores,
    const int* __restrict__ step_ptr, float* __restrict__ out)
{
    const int tid  = threadIdx.x;
    const int lane = tid & 63;
    const int j    = tid >> 6;       // beam 0..7
    const int b    = blockIdx.x;
    const int row  = b * BEAM + j;
    const int step = *step_ptr;

    __shared__ u64 fkey[BEAM * K];
    __shared__ int fvid[BEAM * K];

    // merged row top-16: sort 64 real keys (unique: disjoint vocab ranges)
    u64 v = segk[(size_t)row * (NSEG * K) + lane];
    v = bitonic64_asc_u64(v, lane);
    // lanes 48..63 hold the row top-16 ascending; rank r = 63 - lane

    float* out_s = out;
    float* out_i = out + BSZ * K;
    float* out_b = out + 2 * BSZ * K;

    if (step == 0) {
        // reference: top_k(lprobs[:,0,:]): idx%vocab=idx, idx//vocab=0
        if (j == 0 && lane >= 48) {
            int r = 63 - lane;
            out_s[b * K + r] = s2f((u32)(v >> 32));
            out_i[b * K + r] = (float)(int)~(u32)v;
            out_b[b * K + r] = 0.0f;
        }
        return;
    }

    if (lane >= 48) {
        int r = 63 - lane;
        float val = s2f((u32)(v >> 32));
        float add = scores[row * NSTEP + step - 1];
        float sc  = val + add - (float)(r + 1) * DIV_RATE;
        int c = j * K + r;
        fkey[c] = ((u64)f2s(sc) << 32) | (u32)(127 - c);  // lower c wins ties
        fvid[c] = (int)~(u32)v;
    }
    __syncthreads();

    if (tid < 64) {
        u64 pa = fkey[lane];
        u64 pb = fkey[lane + 64];
        u64 m2 = 0;
#pragma unroll 1
        for (int it = 0; it < K; ++it) {
            u64 mm = wmax64(pa > pb ? pa : pb);
            if (lane == it) m2 = mm;
            if (pa == mm) pa = 0; else if (pb == mm) pb = 0;
        }
        if (lane < K) {
            int c = 127 - (int)(m2 & 0xFFFFFFFFull);
            out_s[b * K + lane] = s2f((u32)(m2 >> 32));
            out_i[b * K + lane] = (float)fvid[c];
            out_b[b * K + lane] = (float)(c >> 4);
        }
    }
}

extern "C" void kernel_launch(void* const* d_in, const int* in_sizes, int n_in,
                              void* d_out, int out_size, void* d_ws, size_t ws_size,
                              hipStream_t stream) {
    const float* lprobs = (const float*)d_in[0];
    const float* scores = (const float*)d_in[1];
    const int*   step   = (const int*)d_in[2];

    u64* segk = (u64*)d_ws;   // 512 rows * 4 segs * 16 keys * 8 B = 256 KB

    dim3 g1(NSEG, BSZ * BEAM);
    rowtop<<<g1, 256, 0, stream>>>(lprobs, segk);
    finalize<<<BSZ, 512, 0, stream>>>(segk, scores, step, (float*)d_out);
}